// Round 2
// baseline (1381.945 us; speedup 1.0000x reference)
//
#include <hip/hip_runtime.h>

// SimpleARRNN: GRU encoder (len<=512) + AR decoder (257 outputs). B=512, I=64, H=100, O=64. fp32.
// Fused affine input paths: W_c = W_ih@W_embed [300x64], b_c = W_ih@b_embed + b_ih
//                           W_d = W_c@W_proj   [300x100], b_d = W_c@b_proj + b_c
// rnn10 (R10): single-barrier step, gate-in-quad. 2 elements/block (long+short, sorted),
// 256 blocks x 512 threads, waves_per_eu(2,2).
// R9 post-mortem: 2 barriers/step + 2 LDS round-trips (h->dots->sdot->gate->h) were the
// structural stall (~2450 cy/step vs ~1170 cy VALU issue); staggering work between the
// two phases changed nothing. R10 removes one round-trip + one barrier:
//   quad q computes ALL 6 rows of gate index q (Whh q,q+100,q+200 + Wc/Wd same) ->
//   DPP quad-reduce leaves all 6 gate inputs in-register -> gate computed inline ->
//   h' written to double-buffered sh. ONE __syncthreads per step. sdot/sbh/sbx deleted.
// Wave uniformity: gate indices padded 100->112 (fake idx: zero weights/biases, h'==0,
// never written). Waves 0..6 = 112 gate quads x 2 elems. Wave 7 = 16 proj quads
// (4 Wproj rows x 2 elems, z stored straight to global; ctx prefetch during encoder).
// h layout: 4 chunks of 25 at stride 28 (chunk bases at banks 0/28/24/20 - disjoint,
// broadcast across quads). Double-buffered; frozen short element keeps parity len1&1.

#define B_  512
#define LC_ 512
#define I_  64
#define H_  100
#define O_  64
#define T_  256
#define H3  300

// ws float offsets
#define WS_WC   0        // [300][64]
#define WS_BC   19200    // [300]
#define WS_WD   19500    // [300][100]
#define WS_BD   49500    // [300]
#define WS_PERM 49800    // int[512]

typedef float v2f __attribute__((ext_vector_type(2)));

__global__ __launch_bounds__(64) void prep1(const float* __restrict__ Wih,
                                            const float* __restrict__ bih,
                                            const float* __restrict__ Wemb,
                                            const float* __restrict__ bemb,
                                            float* __restrict__ ws) {
    int j = blockIdx.x;   // 0..299
    int i = threadIdx.x;  // 0..63
    float acc = 0.f;
    for (int k = 0; k < H_; ++k) acc += Wih[j * H_ + k] * Wemb[k * I_ + i];
    ws[WS_WC + j * I_ + i] = acc;
    if (i == 0) {
        float b = bih[j];
        for (int k = 0; k < H_; ++k) b += Wih[j * H_ + k] * bemb[k];
        ws[WS_BC + j] = b;
    }
}

__global__ __launch_bounds__(128) void prep2(const float* __restrict__ Wproj,
                                             const float* __restrict__ bproj,
                                             float* __restrict__ ws) {
    int j = blockIdx.x;   // 0..299
    int u = threadIdx.x;
    const float* Wc = ws + WS_WC;
    if (u < H_) {
        float acc = 0.f;
        for (int o = 0; o < O_; ++o) acc += Wc[j * I_ + o] * Wproj[o * H_ + u];
        ws[WS_WD + j * H_ + u] = acc;
    }
    if (u == 0) {
        float b = ws[WS_BC + j];
        for (int o = 0; o < O_; ++o) b += Wc[j * I_ + o] * bproj[o];
        ws[WS_BD + j] = b;
    }
}

// rank elements by length descending -> perm (longest first)
__global__ __launch_bounds__(512) void sortk(const int* __restrict__ lens,
                                             int* __restrict__ perm) {
    __shared__ int sl[B_];
    int tid = threadIdx.x;
    sl[tid] = lens[tid];
    __syncthreads();
    int li = sl[tid];
    int rank = 0;
    for (int j = 0; j < B_; ++j) {
        int lj = sl[j];
        rank += (lj > li) || (lj == li && j < tid);
    }
    perm[rank] = tid;
}

__device__ __forceinline__ float sigm_(float x) { return 1.f / (1.f + __expf(-x)); }
__device__ __forceinline__ float tanh_(float x) {
    float t = __expf(-2.f * fabsf(x));
    float r = (1.f - t) / (1.f + t);
    return (x >= 0.f) ? r : -r;
}

template <int CTRL>
__device__ __forceinline__ float dppmov_(float x) {
    return __int_as_float(
        __builtin_amdgcn_mov_dpp(__float_as_int(x), CTRL, 0xF, 0xF, true));
}
// reduce across the 4 lanes of a quad; all 4 lanes end with the sum
__device__ __forceinline__ float red4_(float a) {
    a += dppmov_<0xB1>(a);    // quad_perm [1,0,3,2] = xor1 (involution, verified R5/R7)
    a += dppmov_<0x4E>(a);    // quad_perm [2,3,0,1] = xor2
    return a;
}

// h-row dot: 12 v2f pairs + tail scalar (25 cols), then quad reduce
__device__ __forceinline__ float dotH_(const v2f* __restrict__ w2, float w1,
                                       const v2f* __restrict__ hv2, float h24) {
    v2f a = {0.f, 0.f};
    #pragma unroll
    for (int j = 0; j < 12; ++j) a = w2[j] * hv2[j] + a;   // v_pk_fma_f32
    return red4_(fmaf(w1, h24, a.x + a.y));
}
// ctx-row dot: 8 v2f pairs (16 cols), then quad reduce
__device__ __forceinline__ float dotC_(const v2f* __restrict__ w2,
                                       const v2f* __restrict__ cv2) {
    v2f a = {0.f, 0.f};
    #pragma unroll
    for (int j = 0; j < 8; ++j) a = w2[j] * cv2[j] + a;
    return red4_(a.x + a.y);
}

__global__ __attribute__((amdgpu_flat_work_group_size(512, 512)))
__attribute__((amdgpu_waves_per_eu(2, 2)))
void rnn10(const float* __restrict__ ctx, const int* __restrict__ lens,
           const float* __restrict__ Whh, const float* __restrict__ bhh,
           const float* __restrict__ Wproj, const float* __restrict__ bproj,
           const float* __restrict__ ws, float* __restrict__ out) {

    const int tid = threadIdx.x;
    const int l   = tid & 3;          // quad lane: h-cols 25l..25l+24, ctx-cols 16l..16l+15
    const int g   = tid >> 2;         // quad index 0..127
    const bool wl = (l == 0);

    const int* perm = (const int*)(ws + WS_PERM);
    const int e0 = perm[blockIdx.x];         // long element
    const int e1 = perm[511 - blockIdx.x];   // short element
    const int len0 = lens[e0], len1 = lens[e1];

    __shared__ __align__(16) float sh[2][2][112];    // [elem][buf][4 chunks of 25 @ stride 28]
    __shared__ __align__(16) float sctx[2][2][64];   // [elem][buf][64]

    const bool isG  = (g < 112);      // gate quads (waves 0..6); wave 7 = proj/prefetch
    const bool real = (g < 100);      // fake gate indices 100..111: zero weights, no write
    const int  hslot = real ? (28 * (g / 25) + (g % 25)) : 0;

    // ---- register-resident state ----
    v2f   wh[3][12]; float wh1[3]; float bh[3];   // Whh rows g, g+100, g+200
    v2f   wx[3][12]; float wx1[3]; float bx[3];   // enc: Wc rows (8 v2f); dec: Wd rows
    float hreg0 = 0.f, hreg1 = 0.f;               // own h value per element
    v2f   wp[4][12]; float wp1[4]; float bp[4];   // proj quads: Wproj rows k+16r

    if (isG) {
        #pragma unroll
        for (int r = 0; r < 3; ++r) {
            if (real) {
                const float* p = Whh + (g + 100 * r) * H_ + 25 * l;
                #pragma unroll
                for (int j = 0; j < 12; ++j) wh[r][j] = v2f{p[2 * j], p[2 * j + 1]};
                wh1[r] = p[24];
                bh[r]  = bhh[g + 100 * r];
                const float* pc = ws + WS_WC + (g + 100 * r) * I_ + 16 * l;
                #pragma unroll
                for (int j = 0; j < 8; ++j) wx[r][j] = v2f{pc[2 * j], pc[2 * j + 1]};
                bx[r] = ws[WS_BC + g + 100 * r];
            } else {
                #pragma unroll
                for (int j = 0; j < 12; ++j) { wh[r][j] = v2f{0.f, 0.f}; wx[r][j] = v2f{0.f, 0.f}; }
                wh1[r] = 0.f; wx1[r] = 0.f; bh[r] = 0.f; bx[r] = 0.f;
            }
        }
    } else {
        const int k = g - 112;
        #pragma unroll
        for (int r = 0; r < 4; ++r) {
            const float* p = Wproj + (k + 16 * r) * H_ + 25 * l;
            #pragma unroll
            for (int j = 0; j < 12; ++j) wp[r][j] = v2f{p[2 * j], p[2 * j + 1]};
            wp1[r] = p[24];
            bp[r]  = bproj[k + 16 * r];
        }
    }

    // ---- prefetch lanes (wave 7): lanes 0..15 -> e0, 16..31 -> e1 ----
    const int pl = tid - 448;
    const int pe = (pl >> 4) & 1;
    const int pi = pl & 15;
    const float4* pc0 = (const float4*)(ctx + (size_t)e0 * LC_ * I_);
    const float4* pc1 = (const float4*)(ctx + (size_t)e1 * LC_ * I_);
    const float4* pcm = pe ? pc1 : pc0;
    const int lenp = pe ? len1 : len0;
    float4 pf = {0.f, 0.f, 0.f, 0.f};

    float* oute0 = out + (size_t)e0 * (T_ + 1) * O_;
    float* oute1 = out + (size_t)e1 * (T_ + 1) * O_;

    // ---- init: zero both h buffers; stage ctx[0] and prefetch ctx[1] ----
    if (tid < 448) ((float*)sh)[tid] = 0.f;
    if (!isG && pl < 32) {
        *(float4*)&sctx[pe][0][4 * pi] = pcm[pi];
        if (1 < lenp) pf = pcm[16 + pi];
    }
    __syncthreads();

    // ---- hv loader ----
    auto loadH = [&](int e, int b, v2f* hv2, float& h24) {
        #pragma unroll
        for (int q = 0; q < 6; ++q) {
            float4 f = *(const float4*)&sh[e][b][28 * l + 4 * q];
            hv2[2 * q]     = v2f{f.x, f.y};
            hv2[2 * q + 1] = v2f{f.z, f.w};
        }
        h24 = sh[e][b][28 * l + 24];
    };

    // ================ encoder: t = 0 .. len0-1 (one barrier per step) ================
    for (int t = 0; t < len0; ++t) {
        const int rb = t & 1, wb = rb ^ 1;
        if (isG) {
            {   // e0 (always live)
                v2f hv2[12], cv2[8]; float h24;
                loadH(0, rb, hv2, h24);
                #pragma unroll
                for (int q = 0; q < 4; ++q) {
                    float4 f = *(const float4*)&sctx[0][rb][16 * l + 4 * q];
                    cv2[2 * q]     = v2f{f.x, f.y};
                    cv2[2 * q + 1] = v2f{f.z, f.w};
                }
                float gr = dotH_(wh[0], wh1[0], hv2, h24) + bh[0];
                float gz = dotH_(wh[1], wh1[1], hv2, h24) + bh[1];
                float gn = dotH_(wh[2], wh1[2], hv2, h24) + bh[2];
                float xr = dotC_(wx[0], cv2) + bx[0];
                float xz = dotC_(wx[1], cv2) + bx[1];
                float xn = dotC_(wx[2], cv2) + bx[2];
                float r = sigm_(xr + gr);
                float z = sigm_(xz + gz);
                float n = tanh_(xn + r * gn);
                hreg0 = (1.f - z) * n + z * hreg0;
                if (wl && real) sh[0][wb][hslot] = hreg0;
            }
            if (t < len1) {   // e1 (block-uniform liveness)
                v2f hv2[12], cv2[8]; float h24;
                loadH(1, rb, hv2, h24);
                #pragma unroll
                for (int q = 0; q < 4; ++q) {
                    float4 f = *(const float4*)&sctx[1][rb][16 * l + 4 * q];
                    cv2[2 * q]     = v2f{f.x, f.y};
                    cv2[2 * q + 1] = v2f{f.z, f.w};
                }
                float gr = dotH_(wh[0], wh1[0], hv2, h24) + bh[0];
                float gz = dotH_(wh[1], wh1[1], hv2, h24) + bh[1];
                float gn = dotH_(wh[2], wh1[2], hv2, h24) + bh[2];
                float xr = dotC_(wx[0], cv2) + bx[0];
                float xz = dotC_(wx[1], cv2) + bx[1];
                float xn = dotC_(wx[2], cv2) + bx[2];
                float r = sigm_(xr + gr);
                float z = sigm_(xz + gz);
                float n = tanh_(xn + r * gn);
                hreg1 = (1.f - z) * n + z * hreg1;
                if (wl && real) sh[1][wb][hslot] = hreg1;
            }
        } else if (pl < 32) {   // wave 7: ctx prefetch (write t+1, load t+2)
            if (t + 1 < lenp) *(float4*)&sctx[pe][wb][4 * pi] = pf;
            if (t + 2 < lenp) pf = pcm[(t + 2) * 16 + pi];
        }
        __syncthreads();
    }

    // ---- switch gate input path to decoder (registers only - no barrier needed) ----
    if (isG && real) {
        #pragma unroll
        for (int r = 0; r < 3; ++r) {
            const float* p = ws + WS_WD + (g + 100 * r) * H_ + 25 * l;
            #pragma unroll
            for (int j = 0; j < 12; ++j) wx[r][j] = v2f{p[2 * j], p[2 * j + 1]};
            wx1[r] = p[24];
            bx[r]  = ws[WS_BD + g + 100 * r];
        }
    }

    // ================ decoder: outputs t = 0..256 (one barrier per step) ================
    const int p0 = len0 & 1, p1 = len1 & 1;   // h parity at decoder entry
    for (int t = 0; t <= T_; ++t) {
        const int rb0 = (p0 + t) & 1, rb1 = (p1 + t) & 1;
        if (isG) {
            if (t < T_) {   // h_{t+1} not needed after last output
                {   // e0
                    v2f hv2[12]; float h24;
                    loadH(0, rb0, hv2, h24);
                    float gr = dotH_(wh[0], wh1[0], hv2, h24) + bh[0];
                    float gz = dotH_(wh[1], wh1[1], hv2, h24) + bh[1];
                    float gn = dotH_(wh[2], wh1[2], hv2, h24) + bh[2];
                    float xr = dotH_(wx[0], wx1[0], hv2, h24) + bx[0];
                    float xz = dotH_(wx[1], wx1[1], hv2, h24) + bx[1];
                    float xn = dotH_(wx[2], wx1[2], hv2, h24) + bx[2];
                    float r = sigm_(xr + gr);
                    float z = sigm_(xz + gz);
                    float n = tanh_(xn + r * gn);
                    hreg0 = (1.f - z) * n + z * hreg0;
                    if (wl && real) sh[0][rb0 ^ 1][hslot] = hreg0;
                }
                {   // e1
                    v2f hv2[12]; float h24;
                    loadH(1, rb1, hv2, h24);
                    float gr = dotH_(wh[0], wh1[0], hv2, h24) + bh[0];
                    float gz = dotH_(wh[1], wh1[1], hv2, h24) + bh[1];
                    float gn = dotH_(wh[2], wh1[2], hv2, h24) + bh[2];
                    float xr = dotH_(wx[0], wx1[0], hv2, h24) + bx[0];
                    float xz = dotH_(wx[1], wx1[1], hv2, h24) + bx[1];
                    float xn = dotH_(wx[2], wx1[2], hv2, h24) + bx[2];
                    float r = sigm_(xr + gr);
                    float z = sigm_(xz + gz);
                    float n = tanh_(xn + r * gn);
                    hreg1 = (1.f - z) * n + z * hreg1;
                    if (wl && real) sh[1][rb1 ^ 1][hslot] = hreg1;
                }
            }
        } else {
            // proj wave: z_t = Wproj @ h_t + bproj, stored straight to global.
            const int k = g - 112;
            {   // e0
                v2f hv2[12]; float h24;
                loadH(0, rb0, hv2, h24);
                float s0 = dotH_(wp[0], wp1[0], hv2, h24) + bp[0];
                float s1 = dotH_(wp[1], wp1[1], hv2, h24) + bp[1];
                float s2 = dotH_(wp[2], wp1[2], hv2, h24) + bp[2];
                float s3 = dotH_(wp[3], wp1[3], hv2, h24) + bp[3];
                float v = (l == 0) ? s0 : (l == 1) ? s1 : (l == 2) ? s2 : s3;
                oute0[t * O_ + k + 16 * l] = v;
            }
            {   // e1
                v2f hv2[12]; float h24;
                loadH(1, rb1, hv2, h24);
                float s0 = dotH_(wp[0], wp1[0], hv2, h24) + bp[0];
                float s1 = dotH_(wp[1], wp1[1], hv2, h24) + bp[1];
                float s2 = dotH_(wp[2], wp1[2], hv2, h24) + bp[2];
                float s3 = dotH_(wp[3], wp1[3], hv2, h24) + bp[3];
                float v = (l == 0) ? s0 : (l == 1) ? s1 : (l == 2) ? s2 : s3;
                oute1[t * O_ + k + 16 * l] = v;
            }
        }
        __syncthreads();
    }
}

extern "C" void kernel_launch(void* const* d_in, const int* in_sizes, int n_in,
                              void* d_out, int out_size, void* d_ws, size_t ws_size,
                              hipStream_t stream) {
    (void)in_sizes; (void)n_in; (void)out_size; (void)ws_size;
    const float* ctx  = (const float*)d_in[0];
    const int*   lens = (const int*)d_in[1];
    // d_in[2] = t_steps (256, hardcoded)
    const float* Wemb = (const float*)d_in[3];
    const float* bemb = (const float*)d_in[4];
    const float* Wih  = (const float*)d_in[5];
    const float* bih  = (const float*)d_in[6];
    const float* Whh  = (const float*)d_in[7];
    const float* bhh  = (const float*)d_in[8];
    const float* Wpr  = (const float*)d_in[9];
    const float* bpr  = (const float*)d_in[10];
    float* ws  = (float*)d_ws;
    float* out = (float*)d_out;

    prep1<<<H3, 64, 0, stream>>>(Wih, bih, Wemb, bemb, ws);
    prep2<<<H3, 128, 0, stream>>>(Wpr, bpr, ws);
    sortk<<<1, 512, 0, stream>>>(lens, (int*)(ws + WS_PERM));
    rnn10<<<256, 512, 0, stream>>>(ctx, lens, Whh, bhh, Wpr, bpr, ws, out);
}

// Round 3
// 1332.281 us; speedup vs baseline: 1.0373x; 1.0373x over previous
//
#include <hip/hip_runtime.h>

// SimpleARRNN: GRU encoder (len<=512) + AR decoder (257 outputs). B=512, I=64, H=100, O=64. fp32.
// Fused affine input paths: W_c = W_ih@W_embed [300x64], b_c = W_ih@b_embed + b_ih
//                           W_d = W_c@W_proj   [300x100], b_d = W_c@b_proj + b_c
// rnn11 (R11): R10's single-barrier gate-in-quad structure + spill control.
// R10 post-mortem: structure OK but scratch spills (WRITE_SIZE 33->81.5 MB, VALUBusy 35%):
// scheduler interleaved e0/e1 bodies -> ~250 live VGPRs on top of 150 resident weights.
// R11 fixes:
//  (1) sched_barrier(0) between element bodies: peak live = weights + ONE element's
//      working set (~200 <= 256 budget at 2 waves/EU). No cross-element interleave.
//  (2) decoder out-stores delayed one step, issued at phase START (R10 stored late in
//      phase -> vmcnt(0) drain before s_barrier exposed store-ack latency every step).
// Structure: quad q computes all 6 rows of gate index q -> DPP quad-reduce -> gate
// in-register -> h' to double-buffered sh. ONE __syncthreads per step.
// Waves 0..6 = 112 gate quads (indices padded 100->112, fake = zero weights, no write).
// Wave 7 = 16 proj quads (4 Wproj rows x 2 elems, z->global; ctx prefetch in encoder).
// h layout: 4 chunks of 25 at stride 28 (bases at banks 0/28/24/20, broadcast reads).

#define B_  512
#define LC_ 512
#define I_  64
#define H_  100
#define O_  64
#define T_  256
#define H3  300

// ws float offsets
#define WS_WC   0        // [300][64]
#define WS_BC   19200    // [300]
#define WS_WD   19500    // [300][100]
#define WS_BD   49500    // [300]
#define WS_PERM 49800    // int[512]

typedef float v2f __attribute__((ext_vector_type(2)));

__global__ __launch_bounds__(64) void prep1(const float* __restrict__ Wih,
                                            const float* __restrict__ bih,
                                            const float* __restrict__ Wemb,
                                            const float* __restrict__ bemb,
                                            float* __restrict__ ws) {
    int j = blockIdx.x;   // 0..299
    int i = threadIdx.x;  // 0..63
    float acc = 0.f;
    for (int k = 0; k < H_; ++k) acc += Wih[j * H_ + k] * Wemb[k * I_ + i];
    ws[WS_WC + j * I_ + i] = acc;
    if (i == 0) {
        float b = bih[j];
        for (int k = 0; k < H_; ++k) b += Wih[j * H_ + k] * bemb[k];
        ws[WS_BC + j] = b;
    }
}

__global__ __launch_bounds__(128) void prep2(const float* __restrict__ Wproj,
                                             const float* __restrict__ bproj,
                                             float* __restrict__ ws) {
    int j = blockIdx.x;   // 0..299
    int u = threadIdx.x;
    const float* Wc = ws + WS_WC;
    if (u < H_) {
        float acc = 0.f;
        for (int o = 0; o < O_; ++o) acc += Wc[j * I_ + o] * Wproj[o * H_ + u];
        ws[WS_WD + j * H_ + u] = acc;
    }
    if (u == 0) {
        float b = ws[WS_BC + j];
        for (int o = 0; o < O_; ++o) b += Wc[j * I_ + o] * bproj[o];
        ws[WS_BD + j] = b;
    }
}

// rank elements by length descending -> perm (longest first)
__global__ __launch_bounds__(512) void sortk(const int* __restrict__ lens,
                                             int* __restrict__ perm) {
    __shared__ int sl[B_];
    int tid = threadIdx.x;
    sl[tid] = lens[tid];
    __syncthreads();
    int li = sl[tid];
    int rank = 0;
    for (int j = 0; j < B_; ++j) {
        int lj = sl[j];
        rank += (lj > li) || (lj == li && j < tid);
    }
    perm[rank] = tid;
}

__device__ __forceinline__ float sigm_(float x) { return 1.f / (1.f + __expf(-x)); }
__device__ __forceinline__ float tanh_(float x) {
    float t = __expf(-2.f * fabsf(x));
    float r = (1.f - t) / (1.f + t);
    return (x >= 0.f) ? r : -r;
}

template <int CTRL>
__device__ __forceinline__ float dppmov_(float x) {
    return __int_as_float(
        __builtin_amdgcn_mov_dpp(__float_as_int(x), CTRL, 0xF, 0xF, true));
}
// reduce across the 4 lanes of a quad; all 4 lanes end with the sum
__device__ __forceinline__ float red4_(float a) {
    a += dppmov_<0xB1>(a);    // quad_perm [1,0,3,2] = xor1 (involution, verified R5/R7)
    a += dppmov_<0x4E>(a);    // quad_perm [2,3,0,1] = xor2
    return a;
}

// h-row dot: 12 v2f pairs + tail scalar (25 cols), then quad reduce
__device__ __forceinline__ float dotH_(const v2f* __restrict__ w2, float w1,
                                       const v2f* __restrict__ hv2, float h24) {
    v2f a = {0.f, 0.f};
    #pragma unroll
    for (int j = 0; j < 12; ++j) a = w2[j] * hv2[j] + a;   // v_pk_fma_f32
    return red4_(fmaf(w1, h24, a.x + a.y));
}
// ctx-row dot: 8 v2f pairs (16 cols), then quad reduce
__device__ __forceinline__ float dotC_(const v2f* __restrict__ w2,
                                       const v2f* __restrict__ cv2) {
    v2f a = {0.f, 0.f};
    #pragma unroll
    for (int j = 0; j < 8; ++j) a = w2[j] * cv2[j] + a;
    return red4_(a.x + a.y);
}

__global__ __attribute__((amdgpu_flat_work_group_size(512, 512)))
__attribute__((amdgpu_waves_per_eu(2, 2)))
void rnn11(const float* __restrict__ ctx, const int* __restrict__ lens,
           const float* __restrict__ Whh, const float* __restrict__ bhh,
           const float* __restrict__ Wproj, const float* __restrict__ bproj,
           const float* __restrict__ ws, float* __restrict__ out) {

    const int tid = threadIdx.x;
    const int l   = tid & 3;          // quad lane: h-cols 25l..25l+24, ctx-cols 16l..16l+15
    const int g   = tid >> 2;         // quad index 0..127
    const bool wl = (l == 0);

    const int* perm = (const int*)(ws + WS_PERM);
    const int e0 = perm[blockIdx.x];         // long element
    const int e1 = perm[511 - blockIdx.x];   // short element
    const int len0 = lens[e0], len1 = lens[e1];

    __shared__ __align__(16) float sh[2][2][112];    // [elem][buf][4 chunks of 25 @ stride 28]
    __shared__ __align__(16) float sctx[2][2][64];   // [elem][buf][64]

    const bool isG  = (g < 112);      // gate quads (waves 0..6); wave 7 = proj/prefetch
    const bool real = (g < 100);      // fake gate indices 100..111: zero weights, no write
    const int  hslot = real ? (28 * (g / 25) + (g % 25)) : 0;

    // ---- register-resident state ----
    v2f   wh[3][12]; float wh1[3]; float bh[3];   // Whh rows g, g+100, g+200
    v2f   wx[3][12]; float wx1[3]; float bx[3];   // enc: Wc rows (8 v2f); dec: Wd rows
    float hreg0 = 0.f, hreg1 = 0.f;               // own h value per element
    v2f   wp[4][12]; float wp1[4]; float bp[4];   // proj quads: Wproj rows k+16r

    if (isG) {
        #pragma unroll
        for (int r = 0; r < 3; ++r) {
            if (real) {
                const float* p = Whh + (g + 100 * r) * H_ + 25 * l;
                #pragma unroll
                for (int j = 0; j < 12; ++j) wh[r][j] = v2f{p[2 * j], p[2 * j + 1]};
                wh1[r] = p[24];
                bh[r]  = bhh[g + 100 * r];
                const float* pc = ws + WS_WC + (g + 100 * r) * I_ + 16 * l;
                #pragma unroll
                for (int j = 0; j < 8; ++j) wx[r][j] = v2f{pc[2 * j], pc[2 * j + 1]};
                bx[r] = ws[WS_BC + g + 100 * r];
            } else {
                #pragma unroll
                for (int j = 0; j < 12; ++j) { wh[r][j] = v2f{0.f, 0.f}; wx[r][j] = v2f{0.f, 0.f}; }
                wh1[r] = 0.f; wx1[r] = 0.f; bh[r] = 0.f; bx[r] = 0.f;
            }
        }
    } else {
        const int k = g - 112;
        #pragma unroll
        for (int r = 0; r < 4; ++r) {
            const float* p = Wproj + (k + 16 * r) * H_ + 25 * l;
            #pragma unroll
            for (int j = 0; j < 12; ++j) wp[r][j] = v2f{p[2 * j], p[2 * j + 1]};
            wp1[r] = p[24];
            bp[r]  = bproj[k + 16 * r];
        }
    }

    // ---- prefetch lanes (wave 7): lanes 0..15 -> e0, 16..31 -> e1 ----
    const int pl = tid - 448;
    const int pe = (pl >> 4) & 1;
    const int pi = pl & 15;
    const float4* pc0 = (const float4*)(ctx + (size_t)e0 * LC_ * I_);
    const float4* pc1 = (const float4*)(ctx + (size_t)e1 * LC_ * I_);
    const float4* pcm = pe ? pc1 : pc0;
    const int lenp = pe ? len1 : len0;
    float4 pf = {0.f, 0.f, 0.f, 0.f};

    float* oute0 = out + (size_t)e0 * (T_ + 1) * O_;
    float* oute1 = out + (size_t)e1 * (T_ + 1) * O_;

    // ---- init: zero both h buffers; stage ctx[0] and prefetch ctx[1] ----
    if (tid < 448) ((float*)sh)[tid] = 0.f;
    if (!isG && pl < 32) {
        *(float4*)&sctx[pe][0][4 * pi] = pcm[pi];
        if (1 < lenp) pf = pcm[16 + pi];
    }
    __syncthreads();

    // ---- hv loader ----
    auto loadH = [&](int e, int b, v2f* hv2, float& h24) {
        #pragma unroll
        for (int q = 0; q < 6; ++q) {
            float4 f = *(const float4*)&sh[e][b][28 * l + 4 * q];
            hv2[2 * q]     = v2f{f.x, f.y};
            hv2[2 * q + 1] = v2f{f.z, f.w};
        }
        h24 = sh[e][b][28 * l + 24];
    };

    // ================ encoder: t = 0 .. len0-1 (one barrier per step) ================
    for (int t = 0; t < len0; ++t) {
        const int rb = t & 1, wb = rb ^ 1;
        if (isG) {
            {   // e0 (always live)
                v2f hv2[12], cv2[8]; float h24;
                loadH(0, rb, hv2, h24);
                #pragma unroll
                for (int q = 0; q < 4; ++q) {
                    float4 f = *(const float4*)&sctx[0][rb][16 * l + 4 * q];
                    cv2[2 * q]     = v2f{f.x, f.y};
                    cv2[2 * q + 1] = v2f{f.z, f.w};
                }
                float gr = dotH_(wh[0], wh1[0], hv2, h24) + bh[0];
                float gz = dotH_(wh[1], wh1[1], hv2, h24) + bh[1];
                float gn = dotH_(wh[2], wh1[2], hv2, h24) + bh[2];
                float xr = dotC_(wx[0], cv2) + bx[0];
                float xz = dotC_(wx[1], cv2) + bx[1];
                float xn = dotC_(wx[2], cv2) + bx[2];
                float r = sigm_(xr + gr);
                float z = sigm_(xz + gz);
                float n = tanh_(xn + r * gn);
                hreg0 = (1.f - z) * n + z * hreg0;
                if (wl && real) sh[0][wb][hslot] = hreg0;
            }
            __builtin_amdgcn_sched_barrier(0);   // cap live set: one element at a time
            if (t < len1) {   // e1 (block-uniform liveness)
                v2f hv2[12], cv2[8]; float h24;
                loadH(1, rb, hv2, h24);
                #pragma unroll
                for (int q = 0; q < 4; ++q) {
                    float4 f = *(const float4*)&sctx[1][rb][16 * l + 4 * q];
                    cv2[2 * q]     = v2f{f.x, f.y};
                    cv2[2 * q + 1] = v2f{f.z, f.w};
                }
                float gr = dotH_(wh[0], wh1[0], hv2, h24) + bh[0];
                float gz = dotH_(wh[1], wh1[1], hv2, h24) + bh[1];
                float gn = dotH_(wh[2], wh1[2], hv2, h24) + bh[2];
                float xr = dotC_(wx[0], cv2) + bx[0];
                float xz = dotC_(wx[1], cv2) + bx[1];
                float xn = dotC_(wx[2], cv2) + bx[2];
                float r = sigm_(xr + gr);
                float z = sigm_(xz + gz);
                float n = tanh_(xn + r * gn);
                hreg1 = (1.f - z) * n + z * hreg1;
                if (wl && real) sh[1][wb][hslot] = hreg1;
            }
        } else if (pl < 32) {   // wave 7: ctx prefetch (write t+1, load t+2)
            if (t + 1 < lenp) *(float4*)&sctx[pe][wb][4 * pi] = pf;
            if (t + 2 < lenp) pf = pcm[(t + 2) * 16 + pi];
        }
        __syncthreads();
    }

    // ---- switch gate input path to decoder (registers only - no barrier needed) ----
    if (isG && real) {
        #pragma unroll
        for (int r = 0; r < 3; ++r) {
            const float* p = ws + WS_WD + (g + 100 * r) * H_ + 25 * l;
            #pragma unroll
            for (int j = 0; j < 12; ++j) wx[r][j] = v2f{p[2 * j], p[2 * j + 1]};
            wx1[r] = p[24];
            bx[r]  = ws[WS_BD + g + 100 * r];
        }
    }

    // ================ decoder: outputs t = 0..256 (one barrier per step) ================
    const int p0 = len0 & 1, p1 = len1 & 1;   // h parity at decoder entry
    float zs0 = 0.f, zs1 = 0.f;               // proj wave: previous step's z (delayed store)
    for (int t = 0; t <= T_; ++t) {
        const int rb0 = (p0 + t) & 1, rb1 = (p1 + t) & 1;
        if (isG) {
            if (t < T_) {   // h_{t+1} not needed after last output
                {   // e0
                    v2f hv2[12]; float h24;
                    loadH(0, rb0, hv2, h24);
                    float gr = dotH_(wh[0], wh1[0], hv2, h24) + bh[0];
                    float gz = dotH_(wh[1], wh1[1], hv2, h24) + bh[1];
                    float gn = dotH_(wh[2], wh1[2], hv2, h24) + bh[2];
                    float xr = dotH_(wx[0], wx1[0], hv2, h24) + bx[0];
                    float xz = dotH_(wx[1], wx1[1], hv2, h24) + bx[1];
                    float xn = dotH_(wx[2], wx1[2], hv2, h24) + bx[2];
                    float r = sigm_(xr + gr);
                    float z = sigm_(xz + gz);
                    float n = tanh_(xn + r * gn);
                    hreg0 = (1.f - z) * n + z * hreg0;
                    if (wl && real) sh[0][rb0 ^ 1][hslot] = hreg0;
                }
                __builtin_amdgcn_sched_barrier(0);   // cap live set
                {   // e1
                    v2f hv2[12]; float h24;
                    loadH(1, rb1, hv2, h24);
                    float gr = dotH_(wh[0], wh1[0], hv2, h24) + bh[0];
                    float gz = dotH_(wh[1], wh1[1], hv2, h24) + bh[1];
                    float gn = dotH_(wh[2], wh1[2], hv2, h24) + bh[2];
                    float xr = dotH_(wx[0], wx1[0], hv2, h24) + bx[0];
                    float xz = dotH_(wx[1], wx1[1], hv2, h24) + bx[1];
                    float xn = dotH_(wx[2], wx1[2], hv2, h24) + bx[2];
                    float r = sigm_(xr + gr);
                    float z = sigm_(xz + gz);
                    float n = tanh_(xn + r * gn);
                    hreg1 = (1.f - z) * n + z * hreg1;
                    if (wl && real) sh[1][rb1 ^ 1][hslot] = hreg1;
                }
            }
        } else {
            // proj wave: store PREVIOUS step's z at phase start (ack hides under dots),
            // then compute this step's z = Wproj @ h_t + bproj, kept in regs.
            const int k = g - 112;
            if (t >= 1) {
                oute0[(t - 1) * O_ + k + 16 * l] = zs0;
                oute1[(t - 1) * O_ + k + 16 * l] = zs1;
            }
            float zn0, zn1;
            {   // e0
                v2f hv2[12]; float h24;
                loadH(0, rb0, hv2, h24);
                float s0 = dotH_(wp[0], wp1[0], hv2, h24) + bp[0];
                float s1 = dotH_(wp[1], wp1[1], hv2, h24) + bp[1];
                float s2 = dotH_(wp[2], wp1[2], hv2, h24) + bp[2];
                float s3 = dotH_(wp[3], wp1[3], hv2, h24) + bp[3];
                zn0 = (l == 0) ? s0 : (l == 1) ? s1 : (l == 2) ? s2 : s3;
            }
            __builtin_amdgcn_sched_barrier(0);   // cap live set
            {   // e1
                v2f hv2[12]; float h24;
                loadH(1, rb1, hv2, h24);
                float s0 = dotH_(wp[0], wp1[0], hv2, h24) + bp[0];
                float s1 = dotH_(wp[1], wp1[1], hv2, h24) + bp[1];
                float s2 = dotH_(wp[2], wp1[2], hv2, h24) + bp[2];
                float s3 = dotH_(wp[3], wp1[3], hv2, h24) + bp[3];
                zn1 = (l == 0) ? s0 : (l == 1) ? s1 : (l == 2) ? s2 : s3;
            }
            zs0 = zn0; zs1 = zn1;
        }
        __syncthreads();
    }
    // drain: final outputs (t = T_)
    if (!isG) {
        const int k = g - 112;
        oute0[T_ * O_ + k + 16 * l] = zs0;
        oute1[T_ * O_ + k + 16 * l] = zs1;
    }
}

extern "C" void kernel_launch(void* const* d_in, const int* in_sizes, int n_in,
                              void* d_out, int out_size, void* d_ws, size_t ws_size,
                              hipStream_t stream) {
    (void)in_sizes; (void)n_in; (void)out_size; (void)ws_size;
    const float* ctx  = (const float*)d_in[0];
    const int*   lens = (const int*)d_in[1];
    // d_in[2] = t_steps (256, hardcoded)
    const float* Wemb = (const float*)d_in[3];
    const float* bemb = (const float*)d_in[4];
    const float* Wih  = (const float*)d_in[5];
    const float* bih  = (const float*)d_in[6];
    const float* Whh  = (const float*)d_in[7];
    const float* bhh  = (const float*)d_in[8];
    const float* Wpr  = (const float*)d_in[9];
    const float* bpr  = (const float*)d_in[10];
    float* ws  = (float*)d_ws;
    float* out = (float*)d_out;

    prep1<<<H3, 64, 0, stream>>>(Wih, bih, Wemb, bemb, ws);
    prep2<<<H3, 128, 0, stream>>>(Wpr, bpr, ws);
    sortk<<<1, 512, 0, stream>>>(lens, (int*)(ws + WS_PERM));
    rnn11<<<256, 512, 0, stream>>>(ctx, lens, Whh, bhh, Wpr, bpr, ws, out);
}

// Round 4
// 763.338 us; speedup vs baseline: 1.8104x; 1.7453x over previous
//
#include <hip/hip_runtime.h>

// SimpleARRNN: GRU encoder (len<=512) + AR decoder (257 outputs). B=512, I=64, H=100, O=64. fp32.
// Fused affine input paths: W_c = W_ih@W_embed [300x64], b_c = W_ih@b_embed + b_ih
//                           W_d = W_c@W_proj   [300x100], b_d = W_c@b_proj + b_c
// rnn12 (R12): single-barrier gate-in-quad + UNIFIED weight register file.
// R10/R11 post-mortem: wave 7's separate wp[4][12]+bp arrays coexisted with gate waves'
// wh/wx in the static allocation (divergent branches both live across the loops) ->
// ~212 resident + working set > 256-VGPR budget -> scratch spills in the serial chain
// (WRITE_SIZE 33->81 MB, 2x step time). R8 never spilled because ALL waves shared one
// w2[6][12] array. R12 restores that: every quad holds w[6][12]+w1[6]+b[6];
//   gate quads g<100: w[0..2]=Whh rows g,g+100,g+200; w[3..5]=Wc(enc,8v2f)/Wd(dec);
//   fake quads 100..111: zeros (wave-uniformity pad);
//   proj quads 112..127: w[0..3]=Wproj rows k+16r, b=bproj (same dot code, z epilogue).
// Quad-local gate: DPP quad-reduce leaves all 6 gate inputs in-register -> inline gate,
// h' -> double-buffered sh. ONE __syncthreads per step. Decoder z stores delayed one
// step, issued at phase start. sched_barrier(0) between e0/e1 bodies caps live set.
// h layout: 4 chunks of 25 at stride 28 (bases at banks 0/28/24/20, broadcast reads).

#define B_  512
#define LC_ 512
#define I_  64
#define H_  100
#define O_  64
#define T_  256
#define H3  300

// ws float offsets
#define WS_WC   0        // [300][64]
#define WS_BC   19200    // [300]
#define WS_WD   19500    // [300][100]
#define WS_BD   49500    // [300]
#define WS_PERM 49800    // int[512]

typedef float v2f __attribute__((ext_vector_type(2)));

__global__ __launch_bounds__(64) void prep1(const float* __restrict__ Wih,
                                            const float* __restrict__ bih,
                                            const float* __restrict__ Wemb,
                                            const float* __restrict__ bemb,
                                            float* __restrict__ ws) {
    int j = blockIdx.x;   // 0..299
    int i = threadIdx.x;  // 0..63
    float acc = 0.f;
    for (int k = 0; k < H_; ++k) acc += Wih[j * H_ + k] * Wemb[k * I_ + i];
    ws[WS_WC + j * I_ + i] = acc;
    if (i == 0) {
        float b = bih[j];
        for (int k = 0; k < H_; ++k) b += Wih[j * H_ + k] * bemb[k];
        ws[WS_BC + j] = b;
    }
}

__global__ __launch_bounds__(128) void prep2(const float* __restrict__ Wproj,
                                             const float* __restrict__ bproj,
                                             float* __restrict__ ws) {
    int j = blockIdx.x;   // 0..299
    int u = threadIdx.x;
    const float* Wc = ws + WS_WC;
    if (u < H_) {
        float acc = 0.f;
        for (int o = 0; o < O_; ++o) acc += Wc[j * I_ + o] * Wproj[o * H_ + u];
        ws[WS_WD + j * H_ + u] = acc;
    }
    if (u == 0) {
        float b = ws[WS_BC + j];
        for (int o = 0; o < O_; ++o) b += Wc[j * I_ + o] * bproj[o];
        ws[WS_BD + j] = b;
    }
}

// rank elements by length descending -> perm (longest first)
__global__ __launch_bounds__(512) void sortk(const int* __restrict__ lens,
                                             int* __restrict__ perm) {
    __shared__ int sl[B_];
    int tid = threadIdx.x;
    sl[tid] = lens[tid];
    __syncthreads();
    int li = sl[tid];
    int rank = 0;
    for (int j = 0; j < B_; ++j) {
        int lj = sl[j];
        rank += (lj > li) || (lj == li && j < tid);
    }
    perm[rank] = tid;
}

__device__ __forceinline__ float sigm_(float x) { return 1.f / (1.f + __expf(-x)); }
__device__ __forceinline__ float tanh_(float x) {
    float t = __expf(-2.f * fabsf(x));
    float r = (1.f - t) / (1.f + t);
    return (x >= 0.f) ? r : -r;
}

template <int CTRL>
__device__ __forceinline__ float dppmov_(float x) {
    return __int_as_float(
        __builtin_amdgcn_mov_dpp(__float_as_int(x), CTRL, 0xF, 0xF, true));
}
// reduce across the 4 lanes of a quad; all 4 lanes end with the sum
__device__ __forceinline__ float red4_(float a) {
    a += dppmov_<0xB1>(a);    // quad_perm [1,0,3,2] = xor1 (involution, verified R5/R7)
    a += dppmov_<0x4E>(a);    // quad_perm [2,3,0,1] = xor2
    return a;
}

// h-row dot: 12 v2f pairs + tail scalar (25 cols), then quad reduce
__device__ __forceinline__ float dotH_(const v2f* __restrict__ w2, float w1,
                                       const v2f* __restrict__ hv2, float h24) {
    v2f a = {0.f, 0.f};
    #pragma unroll
    for (int j = 0; j < 12; ++j) a = w2[j] * hv2[j] + a;   // v_pk_fma_f32
    return red4_(fmaf(w1, h24, a.x + a.y));
}
// ctx-row dot: 8 v2f pairs (16 cols), then quad reduce
__device__ __forceinline__ float dotC_(const v2f* __restrict__ w2,
                                       const v2f* __restrict__ cv2) {
    v2f a = {0.f, 0.f};
    #pragma unroll
    for (int j = 0; j < 8; ++j) a = w2[j] * cv2[j] + a;
    return red4_(a.x + a.y);
}

__global__ __attribute__((amdgpu_flat_work_group_size(512, 512)))
__attribute__((amdgpu_waves_per_eu(2, 2)))
void rnn12(const float* __restrict__ ctx, const int* __restrict__ lens,
           const float* __restrict__ Whh, const float* __restrict__ bhh,
           const float* __restrict__ Wproj, const float* __restrict__ bproj,
           const float* __restrict__ ws, float* __restrict__ out) {

    const int tid = threadIdx.x;
    const int l   = tid & 3;          // quad lane: h-cols 25l..25l+24, ctx-cols 16l..16l+15
    const int g   = tid >> 2;         // quad index 0..127
    const bool wl = (l == 0);

    const int* perm = (const int*)(ws + WS_PERM);
    const int e0 = perm[blockIdx.x];         // long element
    const int e1 = perm[511 - blockIdx.x];   // short element
    const int len0 = lens[e0], len1 = lens[e1];

    __shared__ __align__(16) float sh[2][2][112];    // [elem][buf][4 chunks of 25 @ stride 28]
    __shared__ __align__(16) float sctx[2][2][64];   // [elem][buf][64]

    const bool isG  = (g < 112);      // gate quads (waves 0..6); wave 7 = proj/prefetch
    const bool real = (g < 100);      // fake gate indices 100..111: zero weights, no write
    const int  hslot = real ? (28 * (g / 25) + (g % 25)) : 0;

    // ---- UNIFIED register-resident weight file (identical shape for every thread) ----
    v2f   w[6][12]; float w1[6]; float b[6];
    float hreg0 = 0.f, hreg1 = 0.f;   // gate quads: own h | proj quads: unused
    float zs0 = 0.f, zs1 = 0.f;       // proj quads: delayed z store

    #pragma unroll
    for (int r = 0; r < 6; ++r) {
        #pragma unroll
        for (int j = 0; j < 12; ++j) w[r][j] = v2f{0.f, 0.f};
        w1[r] = 0.f; b[r] = 0.f;
    }
    if (real) {   // gate quads: Whh rows + Wc rows (enc input path)
        #pragma unroll
        for (int r = 0; r < 3; ++r) {
            const float* p = Whh + (g + 100 * r) * H_ + 25 * l;
            #pragma unroll
            for (int j = 0; j < 12; ++j) w[r][j] = v2f{p[2 * j], p[2 * j + 1]};
            w1[r] = p[24];
            b[r]  = bhh[g + 100 * r];
            const float* pc = ws + WS_WC + (g + 100 * r) * I_ + 16 * l;
            #pragma unroll
            for (int j = 0; j < 8; ++j) w[3 + r][j] = v2f{pc[2 * j], pc[2 * j + 1]};
            b[3 + r] = ws[WS_BC + g + 100 * r];
        }
    } else if (!isG) {   // proj quads: Wproj rows k+16r in w[0..3]
        const int k = g - 112;
        #pragma unroll
        for (int r = 0; r < 4; ++r) {
            const float* p = Wproj + (k + 16 * r) * H_ + 25 * l;
            #pragma unroll
            for (int j = 0; j < 12; ++j) w[r][j] = v2f{p[2 * j], p[2 * j + 1]};
            w1[r] = p[24];
            b[r]  = bproj[k + 16 * r];
        }
    }

    // ---- prefetch lanes (wave 7): lanes 0..15 -> e0, 16..31 -> e1 ----
    const int pl = tid - 448;
    const int pe = (pl >> 4) & 1;
    const int pi = pl & 15;
    const float4* pc0 = (const float4*)(ctx + (size_t)e0 * LC_ * I_);
    const float4* pc1 = (const float4*)(ctx + (size_t)e1 * LC_ * I_);
    const float4* pcm = pe ? pc1 : pc0;
    const int lenp = pe ? len1 : len0;
    float4 pf = {0.f, 0.f, 0.f, 0.f};

    float* oute0 = out + (size_t)e0 * (T_ + 1) * O_;
    float* oute1 = out + (size_t)e1 * (T_ + 1) * O_;

    // ---- init: zero both h buffers; stage ctx[0] and prefetch ctx[1] ----
    if (tid < 448) ((float*)sh)[tid] = 0.f;
    if (!isG && pl < 32) {
        *(float4*)&sctx[pe][0][4 * pi] = pcm[pi];
        if (1 < lenp) pf = pcm[16 + pi];
    }
    __syncthreads();

    // ---- hv loader ----
    auto loadH = [&](int e, int bf, v2f* hv2, float& h24) {
        #pragma unroll
        for (int q = 0; q < 6; ++q) {
            float4 f = *(const float4*)&sh[e][bf][28 * l + 4 * q];
            hv2[2 * q]     = v2f{f.x, f.y};
            hv2[2 * q + 1] = v2f{f.z, f.w};
        }
        h24 = sh[e][bf][28 * l + 24];
    };

    // ================ encoder: t = 0 .. len0-1 (one barrier per step) ================
    for (int t = 0; t < len0; ++t) {
        const int rb = t & 1, wb = rb ^ 1;
        if (isG) {
            {   // e0 (always live): h-dots first, then ctx-dots (hv2/cv2 don't overlap)
                v2f hv2[12]; float h24;
                loadH(0, rb, hv2, h24);
                float d0 = dotH_(w[0], w1[0], hv2, h24) + b[0];
                float d1 = dotH_(w[1], w1[1], hv2, h24) + b[1];
                float d2 = dotH_(w[2], w1[2], hv2, h24) + b[2];
                v2f cv2[8];
                #pragma unroll
                for (int q = 0; q < 4; ++q) {
                    float4 f = *(const float4*)&sctx[0][rb][16 * l + 4 * q];
                    cv2[2 * q]     = v2f{f.x, f.y};
                    cv2[2 * q + 1] = v2f{f.z, f.w};
                }
                float d3 = dotC_(w[3], cv2) + b[3];
                float d4 = dotC_(w[4], cv2) + b[4];
                float d5 = dotC_(w[5], cv2) + b[5];
                float r = sigm_(d3 + d0);
                float z = sigm_(d4 + d1);
                float n = tanh_(d5 + r * d2);
                hreg0 = (1.f - z) * n + z * hreg0;
                if (wl && real) sh[0][wb][hslot] = hreg0;
            }
            __builtin_amdgcn_sched_barrier(0);   // cap live set: one element at a time
            if (t < len1) {   // e1 (block-uniform liveness)
                v2f hv2[12]; float h24;
                loadH(1, rb, hv2, h24);
                float d0 = dotH_(w[0], w1[0], hv2, h24) + b[0];
                float d1 = dotH_(w[1], w1[1], hv2, h24) + b[1];
                float d2 = dotH_(w[2], w1[2], hv2, h24) + b[2];
                v2f cv2[8];
                #pragma unroll
                for (int q = 0; q < 4; ++q) {
                    float4 f = *(const float4*)&sctx[1][rb][16 * l + 4 * q];
                    cv2[2 * q]     = v2f{f.x, f.y};
                    cv2[2 * q + 1] = v2f{f.z, f.w};
                }
                float d3 = dotC_(w[3], cv2) + b[3];
                float d4 = dotC_(w[4], cv2) + b[4];
                float d5 = dotC_(w[5], cv2) + b[5];
                float r = sigm_(d3 + d0);
                float z = sigm_(d4 + d1);
                float n = tanh_(d5 + r * d2);
                hreg1 = (1.f - z) * n + z * hreg1;
                if (wl && real) sh[1][wb][hslot] = hreg1;
            }
        } else if (pl < 32) {   // wave 7: ctx prefetch (write t+1, load t+2)
            if (t + 1 < lenp) *(float4*)&sctx[pe][wb][4 * pi] = pf;
            if (t + 2 < lenp) pf = pcm[(t + 2) * 16 + pi];
        }
        __syncthreads();
    }

    // ---- switch gate input path to decoder: Wd rows + bd (registers only) ----
    if (real) {
        #pragma unroll
        for (int r = 0; r < 3; ++r) {
            const float* p = ws + WS_WD + (g + 100 * r) * H_ + 25 * l;
            #pragma unroll
            for (int j = 0; j < 12; ++j) w[3 + r][j] = v2f{p[2 * j], p[2 * j + 1]};
            w1[3 + r] = p[24];
            b[3 + r]  = ws[WS_BD + g + 100 * r];
        }
    }

    // ================ decoder: outputs t = 0..256 (one barrier per step) ================
    const int p0 = len0 & 1, p1 = len1 & 1;   // h parity at decoder entry
    for (int t = 0; t <= T_; ++t) {
        const int rb0 = (p0 + t) & 1, rb1 = (p1 + t) & 1;
        // proj quads: store PREVIOUS step's z at phase start (ack hides under dots)
        if (!isG && t >= 1) {
            const int k = g - 112;
            oute0[(t - 1) * O_ + k + 16 * l] = zs0;
            oute1[(t - 1) * O_ + k + 16 * l] = zs1;
        }
        if (isG ? (t < T_) : true) {   // gate quads skip last iter (h_{T+1} unneeded)
            {   // e0
                v2f hv2[12]; float h24;
                loadH(0, rb0, hv2, h24);
                float d0 = dotH_(w[0], w1[0], hv2, h24) + b[0];
                float d1 = dotH_(w[1], w1[1], hv2, h24) + b[1];
                float d2 = dotH_(w[2], w1[2], hv2, h24) + b[2];
                float d3 = dotH_(w[3], w1[3], hv2, h24) + b[3];
                float d4 = dotH_(w[4], w1[4], hv2, h24) + b[4];
                float d5 = dotH_(w[5], w1[5], hv2, h24) + b[5];
                if (isG) {
                    float r = sigm_(d3 + d0);
                    float z = sigm_(d4 + d1);
                    float n = tanh_(d5 + r * d2);
                    hreg0 = (1.f - z) * n + z * hreg0;
                    if (wl && real) sh[0][rb0 ^ 1][hslot] = hreg0;
                } else {
                    zs0 = (l == 0) ? d0 : (l == 1) ? d1 : (l == 2) ? d2 : d3;
                }
            }
            __builtin_amdgcn_sched_barrier(0);   // cap live set
            {   // e1
                v2f hv2[12]; float h24;
                loadH(1, rb1, hv2, h24);
                float d0 = dotH_(w[0], w1[0], hv2, h24) + b[0];
                float d1 = dotH_(w[1], w1[1], hv2, h24) + b[1];
                float d2 = dotH_(w[2], w1[2], hv2, h24) + b[2];
                float d3 = dotH_(w[3], w1[3], hv2, h24) + b[3];
                float d4 = dotH_(w[4], w1[4], hv2, h24) + b[4];
                float d5 = dotH_(w[5], w1[5], hv2, h24) + b[5];
                if (isG) {
                    float r = sigm_(d3 + d0);
                    float z = sigm_(d4 + d1);
                    float n = tanh_(d5 + r * d2);
                    hreg1 = (1.f - z) * n + z * hreg1;
                    if (wl && real) sh[1][rb1 ^ 1][hslot] = hreg1;
                } else {
                    zs1 = (l == 0) ? d0 : (l == 1) ? d1 : (l == 2) ? d2 : d3;
                }
            }
        }
        __syncthreads();
    }
    // drain: final outputs (t = T_)
    if (!isG) {
        const int k = g - 112;
        oute0[T_ * O_ + k + 16 * l] = zs0;
        oute1[T_ * O_ + k + 16 * l] = zs1;
    }
}

extern "C" void kernel_launch(void* const* d_in, const int* in_sizes, int n_in,
                              void* d_out, int out_size, void* d_ws, size_t ws_size,
                              hipStream_t stream) {
    (void)in_sizes; (void)n_in; (void)out_size; (void)ws_size;
    const float* ctx  = (const float*)d_in[0];
    const int*   lens = (const int*)d_in[1];
    // d_in[2] = t_steps (256, hardcoded)
    const float* Wemb = (const float*)d_in[3];
    const float* bemb = (const float*)d_in[4];
    const float* Wih  = (const float*)d_in[5];
    const float* bih  = (const float*)d_in[6];
    const float* Whh  = (const float*)d_in[7];
    const float* bhh  = (const float*)d_in[8];
    const float* Wpr  = (const float*)d_in[9];
    const float* bpr  = (const float*)d_in[10];
    float* ws  = (float*)d_ws;
    float* out = (float*)d_out;

    prep1<<<H3, 64, 0, stream>>>(Wih, bih, Wemb, bemb, ws);
    prep2<<<H3, 128, 0, stream>>>(Wpr, bpr, ws);
    sortk<<<1, 512, 0, stream>>>(lens, (int*)(ws + WS_PERM));
    rnn12<<<256, 512, 0, stream>>>(ctx, lens, Whh, bhh, Wpr, bpr, ws, out);
}